// Round 1
// baseline (127.911 us; speedup 1.0000x reference)
//
#include <hip/hip_runtime.h>

#define Bv_ 8
#define LQ 128
#define LK 256
#define Dv 32
#define ET 32
#define Hh 8
#define NH 64

// ---------------------------------------------------------------------------
// Kernel 1: prep
//  blocks [0, B*LK)            : per-(b,k) value-MLP -> A, Bdv, mf
//  blocks [B*LK, B*LK+1536)    : time-embedding rows (2 rows/block) -> qe, ke
// ---------------------------------------------------------------------------
__global__ __launch_bounds__(64) void prep_kernel(
    const float* __restrict__ qtt, const float* __restrict__ ktt,
    const float* __restrict__ value, const int* __restrict__ emb_mask,
    const float* __restrict__ w_time, const float* __restrict__ b_time,
    const float* __restrict__ w_per, const float* __restrict__ b_per,
    const float* __restrict__ vt_w1, const float* __restrict__ vt_b1,
    const float* __restrict__ ln_g, const float* __restrict__ ln_b,
    const float* __restrict__ vt_w2, const float* __restrict__ vt_b2,
    const float* __restrict__ wq, const float* __restrict__ bq,
    const float* __restrict__ wk, const float* __restrict__ bk,
    float* __restrict__ A, float* __restrict__ Bdv, float* __restrict__ mf,
    float* __restrict__ qe, float* __restrict__ ke)
{
    const int t = threadIdx.x;
    const int blk = blockIdx.x;

    if (blk < Bv_ * LK) {
        // ---- value-MLP for one (b,k) row ----
        __shared__ float vrow[Dv];
        __shared__ float hrow[NH];
        const int row = blk;                       // b*LK + k
        if (t < Dv) vrow[t] = value[row * Dv + t];
        __syncthreads();

        // hdn[t] = value_row @ vt_w1[:, t] + b1[t]
        float h = vt_b1[t];
        #pragma unroll
        for (int d = 0; d < Dv; ++d) h += vrow[d] * vt_w1[d * NH + t];

        // LayerNorm over NH=64 (block is exactly one wave64)
        float s = h;
        #pragma unroll
        for (int off = 32; off > 0; off >>= 1) s += __shfl_xor(s, off);
        const float mu = s * (1.0f / NH);
        const float dc = h - mu;
        float vs = dc * dc;
        #pragma unroll
        for (int off = 32; off > 0; off >>= 1) vs += __shfl_xor(vs, off);
        const float var = vs * (1.0f / NH);
        const float rs = rsqrtf(var + 1e-5f);
        float hn = dc * rs * ln_g[t] + ln_b[t];
        hn = fmaxf(hn, 0.0f);                      // relu
        hrow[t] = hn;
        __syncthreads();

        if (t < Dv) {
            float dval = vt_b2[t];
            #pragma unroll
            for (int j = 0; j < NH; ++j) dval += hrow[j] * vt_w2[j * Dv + t];
            const int m = emb_mask[row * Dv + t];
            const float mm = (m != 0) ? 1.0f : 0.0f;
            A[row * Dv + t]   = mm * vrow[t];      // m * value
            Bdv[row * Dv + t] = mm * dval;         // m * d_value
            mf[row * Dv + t]  = mm;
        }
    } else {
        // ---- time-embedding + projection, 2 rows per block ----
        const int idx = blk - Bv_ * LK;
        const int sub = t >> 5;                    // 0 or 1
        const int j = t & 31;
        const int row = idx * 2 + sub;             // 0 .. 3071
        __shared__ float eb[2][ET];

        float tt;
        const float *W, *bias;
        float* outp;
        if (row < Bv_ * LQ) {
            tt = qtt[row];
            W = wq; bias = bq; outp = qe + row * ET;
        } else {
            const int r2 = row - Bv_ * LQ;
            tt = ktt[r2];
            W = wk; bias = bk; outp = ke + r2 * ET;
        }
        float e;
        if (j == 0) e = tt * w_time[0] + b_time[0];
        else        e = sinf(tt * w_per[j - 1] + b_per[j - 1]);
        eb[sub][j] = e;
        __syncthreads();

        float o = bias[j];
        #pragma unroll
        for (int i = 0; i < ET; ++i) o += eb[sub][i] * W[i * ET + j];
        outp[j] = o;
    }
}

// ---------------------------------------------------------------------------
// Kernel 2: attention + output projection. One block per (b,q), 256 threads.
// ---------------------------------------------------------------------------
__global__ __launch_bounds__(256) void attn_kernel(
    const float* __restrict__ qtt, const float* __restrict__ ktt,
    const float* __restrict__ w_decay,
    const float* __restrict__ A, const float* __restrict__ Bdv,
    const float* __restrict__ mf,
    const float* __restrict__ qe, const float* __restrict__ ke,
    const float* __restrict__ wo, const float* __restrict__ bo,
    float* __restrict__ out)
{
    __shared__ float Eh[Hh][LK];    // exp(scores), per head
    __shared__ float gk[LK];        // dt/(1+wd*dt)
    __shared__ float qrow[ET];
    __shared__ float xsh[Hh * Dv];  // x, flattened c = h*32 + d
    __shared__ float psum[4][NH];

    const int t = threadIdx.x;
    const int bq_ = blockIdx.x;     // b*LQ + q
    const int b = bq_ >> 7;

    // ---- phase 1: scores -> exp, and decay factor g[k] ----
    if (t < ET) qrow[t] = qe[bq_ * ET + t];
    {
        const float dt = qtt[bq_] - ktt[b * LK + t];
        gk[t] = dt / (1.0f + w_decay[0] * dt);
    }
    __syncthreads();
    {
        const float4* kerow = (const float4*)(ke + (b * LK + t) * ET);
        #pragma unroll
        for (int h = 0; h < Hh; ++h) {
            const float4 kk = kerow[h];
            const float sc = 0.5f * (qrow[4*h]   * kk.x + qrow[4*h+1] * kk.y +
                                     qrow[4*h+2] * kk.z + qrow[4*h+3] * kk.w);
            Eh[h][t] = expf(sc);    // |sc| small -> no max subtraction needed
        }
    }
    __syncthreads();

    // ---- phase 2: per-(h,d) reduction over k ----
    {
        const int h = t >> 5, d = t & 31;
        const float* Ab = A   + b * LK * Dv + d;
        const float* Bb = Bdv + b * LK * Dv + d;
        const float* Mb = mf  + b * LK * Dv + d;
        float num = 0.0f, den = 0.0f;
        #pragma unroll 8
        for (int k = 0; k < LK; ++k) {
            const float e = Eh[h][k];
            const float a = Ab[k * Dv];
            const float bb = Bb[k * Dv];
            const float m = Mb[k * Dv];
            num += e * (a + gk[k] * bb);
            den += e * m;
        }
        xsh[t] = num / fmaxf(den, 1e-30f);
    }
    __syncthreads();

    // ---- phase 3: out[b,q,:] = x @ wo + bo ----
    {
        const int j = t & 63, quarter = t >> 6;
        float p = 0.0f;
        #pragma unroll
        for (int c0 = 0; c0 < 64; ++c0) {
            const int c = quarter * 64 + c0;
            p += xsh[c] * wo[c * NH + j];
        }
        psum[quarter][j] = p;
    }
    __syncthreads();
    if (t < NH) {
        out[bq_ * NH + t] = bo[t] + psum[0][t] + psum[1][t] + psum[2][t] + psum[3][t];
    }
}

extern "C" void kernel_launch(void* const* d_in, const int* in_sizes, int n_in,
                              void* d_out, int out_size, void* d_ws, size_t ws_size,
                              hipStream_t stream) {
    const float* qtt      = (const float*)d_in[0];
    const float* ktt      = (const float*)d_in[1];
    const float* value    = (const float*)d_in[2];
    const int*   emb_mask = (const int*)  d_in[3];
    const float* w_time   = (const float*)d_in[4];
    const float* b_time   = (const float*)d_in[5];
    const float* w_per    = (const float*)d_in[6];
    const float* b_per    = (const float*)d_in[7];
    const float* w_decay  = (const float*)d_in[8];
    const float* vt_w1    = (const float*)d_in[9];
    const float* vt_b1    = (const float*)d_in[10];
    const float* ln_g     = (const float*)d_in[11];
    const float* ln_b     = (const float*)d_in[12];
    const float* vt_w2    = (const float*)d_in[13];
    const float* vt_b2    = (const float*)d_in[14];
    const float* wq       = (const float*)d_in[15];
    const float* bq       = (const float*)d_in[16];
    const float* wk       = (const float*)d_in[17];
    const float* bk       = (const float*)d_in[18];
    const float* wo       = (const float*)d_in[19];
    const float* bo       = (const float*)d_in[20];
    float* out = (float*)d_out;

    float* ws  = (float*)d_ws;
    float* Aw  = ws;                 // 65536
    float* Bw  = ws + 65536;         // 65536
    float* Mw  = ws + 131072;        // 65536
    float* qew = ws + 196608;        // 32768
    float* kew = ws + 229376;        // 65536

    const int nblk_prep = Bv_ * LK + (Bv_ * LQ + Bv_ * LK) / 2;  // 2048 + 1536
    hipLaunchKernelGGL(prep_kernel, dim3(nblk_prep), dim3(64), 0, stream,
                       qtt, ktt, value, emb_mask, w_time, b_time, w_per, b_per,
                       vt_w1, vt_b1, ln_g, ln_b, vt_w2, vt_b2,
                       wq, bq, wk, bk, Aw, Bw, Mw, qew, kew);

    hipLaunchKernelGGL(attn_kernel, dim3(Bv_ * LQ), dim3(256), 0, stream,
                       qtt, ktt, w_decay, Aw, Bw, Mw, qew, kew, wo, bo, out);
}